// Round 1
// baseline (437.209 us; speedup 1.0000x reference)
//
#include <hip/hip_runtime.h>
#include <math.h>

#define N_NODES 50000
#define N_EDGES 500000
#define DIM 64
#define NUM_RELS 16
#define GPB 64   // groups per relation: grid = 16*GPB = 1024 blocks = 4 blocks/CU

// ---------------- ws layout (4-byte units) ----------------
// [0,192)        uvecs: u_s[64], v_e[64], u_d[64]
// [192,208)      counts[16]
// [208,225)      offs[17]
// [228,244)      cursor[16]
// [256,256+N)    snode[N]
// [256+N,256+2N) dnode[N]
// [256+2N, +E)   perm[E]
// total ~2.4 MB

// K0: fold W_attn through W_shared; zero counters.
__global__ void k0_prep(const float* __restrict__ W_shared,
                        const float* __restrict__ W_attn,
                        float* __restrict__ uvecs,
                        int* __restrict__ counts,
                        int* __restrict__ cursor) {
    int t = threadIdx.x;
    if (t < 64) {
        float us = 0.f, ve = 0.f, ud = 0.f;
        for (int o = 0; o < 64; ++o) {
            float w = W_shared[o * 64 + t];
            us = fmaf(w, W_attn[o],        us);
            ve = fmaf(w, W_attn[64 + o],   ve);
            ud = fmaf(w, W_attn[128 + o],  ud);
        }
        uvecs[t] = us; uvecs[64 + t] = ve; uvecs[128 + t] = ud;
    } else if (t < 80) {
        counts[t - 64] = 0;
    } else if (t < 96) {
        cursor[t - 80] = 0;
    }
}

// K1: per-node score scalars s[n]=h[n]·u_s, d[n]=h[n]·u_d
__global__ void k1_node(const float* __restrict__ h,
                        const float* __restrict__ uvecs,
                        float* __restrict__ sn, float* __restrict__ dn) {
    int n = blockIdx.x * blockDim.x + threadIdx.x;
    if (n >= N_NODES) return;
    const float* hp = h + (size_t)n * DIM;
    float s = 0.f, d = 0.f;
#pragma unroll
    for (int i = 0; i < 64; i += 4) {
        float4 t = *(const float4*)(hp + i);
        s = fmaf(t.x, uvecs[i],     s); s = fmaf(t.y, uvecs[i + 1], s);
        s = fmaf(t.z, uvecs[i + 2], s); s = fmaf(t.w, uvecs[i + 3], s);
        d = fmaf(t.x, uvecs[128 + i],     d); d = fmaf(t.y, uvecs[128 + i + 1], d);
        d = fmaf(t.z, uvecs[128 + i + 2], d); d = fmaf(t.w, uvecs[128 + i + 3], d);
    }
    sn[n] = s; dn[n] = d;
}

// K2: per-relation edge counts (block-local LDS histogram -> 16 global atomics)
__global__ void k2_count(const int* __restrict__ rel, int* __restrict__ counts) {
    __shared__ int hist[NUM_RELS];
    int t = threadIdx.x;
    if (t < NUM_RELS) hist[t] = 0;
    __syncthreads();
    int e = blockIdx.x * blockDim.x + t;
    if (e < N_EDGES) atomicAdd(&hist[rel[e]], 1);
    __syncthreads();
    if (t < NUM_RELS && hist[t]) atomicAdd(&counts[t], hist[t]);
}

// K3: exclusive scan of 16 counts
__global__ void k3_scan(const int* __restrict__ counts, int* __restrict__ offs) {
    if (threadIdx.x == 0) {
        int acc = 0;
        for (int r = 0; r < NUM_RELS; ++r) { offs[r] = acc; acc += counts[r]; }
        offs[NUM_RELS] = acc;
    }
}

// K4: bucket edge ids by relation (block chunk reservation, unordered within relation)
__global__ void k4_scatter(const int* __restrict__ rel,
                           const int* __restrict__ offs,
                           int* __restrict__ cursor,
                           int* __restrict__ perm) {
    __shared__ int hist[NUM_RELS];
    __shared__ int base[NUM_RELS];
    int t = threadIdx.x;
    if (t < NUM_RELS) hist[t] = 0;
    __syncthreads();
    int e = blockIdx.x * blockDim.x + t;
    int r = 0, lpos = 0;
    bool valid = (e < N_EDGES);
    if (valid) { r = rel[e]; lpos = atomicAdd(&hist[r], 1); }
    __syncthreads();
    if (t < NUM_RELS) base[t] = hist[t] ? atomicAdd(&cursor[t], hist[t]) : 0;
    __syncthreads();
    if (valid) perm[offs[r] + base[r] + lpos] = e;
}

// K5: main fused kernel. One wave = one relation; lane o holds W_rel[r][:,o]
// in 64 VGPRs; h[src] row broadcasts via wave-uniform (scalar) loads.
__global__ __launch_bounds__(256, 4) void k5_main(
    const float* __restrict__ h, const float* __restrict__ he,
    const int* __restrict__ src, const int* __restrict__ dst,
    const float* __restrict__ W_rel, const float* __restrict__ uvecs,
    const float* __restrict__ sn, const float* __restrict__ dn,
    const int* __restrict__ offs, const int* __restrict__ perm,
    float* __restrict__ out)
{
    const int lane = threadIdx.x & 63;
    const int wib  = __builtin_amdgcn_readfirstlane(threadIdx.x >> 6);
    const int r    = blockIdx.x & 15;            // consecutive blocks -> different relations
    const int g    = blockIdx.x >> 4;
    const int wr   = g * 4 + wib;                // wave index within relation
    const int stride = GPB * 4;

    // lane's column of W_rel[r]: w[i] = W_rel[r][i][lane]
    float w[64];
    const float* wb = W_rel + (size_t)r * (DIM * DIM) + lane;
#pragma unroll
    for (int i = 0; i < 64; ++i) w[i] = wb[i * 64];

    const float vlane = uvecs[64 + lane];        // v_e component for he-dot

    const int begin = offs[r];
    const int end   = offs[r + 1];

    for (int idx = begin + wr; idx < end; idx += stride) {
        const int e  = __builtin_amdgcn_readfirstlane(perm[idx]);
        const int si = __builtin_amdgcn_readfirstlane(src[e]);
        const int di = __builtin_amdgcn_readfirstlane(dst[e]);

        // a_e = s[src] + d[dst] + he[e]·v_e   (lane-parallel dot + butterfly)
        float p = he[(size_t)e * DIM + lane] * vlane;
#pragma unroll
        for (int m = 32; m > 0; m >>= 1) p += __shfl_xor(p, m, 64);
        const float a = sn[si] + dn[di] + p;

        // out-col o = a * (h[src] · W_rel[r][:,o]); 4 accumulators for ILP
        const float* hp = h + (size_t)si * DIM;
        float a0 = 0.f, a1 = 0.f, a2 = 0.f, a3 = 0.f;
#pragma unroll
        for (int i = 0; i < 64; i += 4) {
            a0 = fmaf(hp[i],     w[i],     a0);
            a1 = fmaf(hp[i + 1], w[i + 1], a1);
            a2 = fmaf(hp[i + 2], w[i + 2], a2);
            a3 = fmaf(hp[i + 3], w[i + 3], a3);
        }
        const float acc = (a0 + a1) + (a2 + a3);

        atomicAdd(out + (size_t)di * DIM + lane, a * acc);
    }
}

// K6: relu in place over the aggregated output
__global__ void k6_relu(float4* __restrict__ out, int n4) {
    int i = blockIdx.x * blockDim.x + threadIdx.x;
    if (i < n4) {
        float4 v = out[i];
        v.x = fmaxf(v.x, 0.f); v.y = fmaxf(v.y, 0.f);
        v.z = fmaxf(v.z, 0.f); v.w = fmaxf(v.w, 0.f);
        out[i] = v;
    }
}

extern "C" void kernel_launch(void* const* d_in, const int* in_sizes, int n_in,
                              void* d_out, int out_size, void* d_ws, size_t ws_size,
                              hipStream_t stream) {
    const float* h        = (const float*)d_in[0];
    const float* he       = (const float*)d_in[1];
    const int*   src      = (const int*)d_in[2];
    const int*   dst      = (const int*)d_in[3];
    const int*   rel      = (const int*)d_in[4];
    const float* W_shared = (const float*)d_in[5];
    const float* W_attn   = (const float*)d_in[6];
    const float* W_rel    = (const float*)d_in[7];
    float*       out      = (float*)d_out;

    float* uvecs  = (float*)d_ws;
    int*   counts = (int*)d_ws + 192;
    int*   offs   = (int*)d_ws + 208;
    int*   cursor = (int*)d_ws + 228;
    float* sn     = (float*)d_ws + 256;
    float* dn     = sn + N_NODES;
    int*   perm   = (int*)(dn + N_NODES);

    hipMemsetAsync(d_out, 0, (size_t)out_size * sizeof(float), stream);

    k0_prep<<<1, 128, 0, stream>>>(W_shared, W_attn, uvecs, counts, cursor);
    k1_node<<<(N_NODES + 255) / 256, 256, 0, stream>>>(h, uvecs, sn, dn);
    k2_count<<<(N_EDGES + 255) / 256, 256, 0, stream>>>(rel, counts);
    k3_scan<<<1, 64, 0, stream>>>(counts, offs);
    k4_scatter<<<(N_EDGES + 255) / 256, 256, 0, stream>>>(rel, offs, cursor, perm);
    k5_main<<<NUM_RELS * GPB, 256, 0, stream>>>(h, he, src, dst, W_rel, uvecs,
                                                sn, dn, offs, perm, out);
    int n4 = out_size / 4;
    k6_relu<<<(n4 + 255) / 256, 256, 0, stream>>>((float4*)out, n4);
}

// Round 2
// 364.615 us; speedup vs baseline: 1.1991x; 1.1991x over previous
//
#include <hip/hip_runtime.h>
#include <math.h>

#define N_NODES 50000
#define N_EDGES 500000
#define DIM 64
#define NUM_RELS 16
#define GPB 64   // 16*GPB = 1024 blocks for k5

// ---------------- ws layout (4-byte units) ----------------
// [0,192)          uvecs: u_s[64], v_e[64], u_d[64]
// [192,208)        counts[16]
// [208,225)        offs[17]
// [228,244)        cursor[16]
// [256, +N)        sn[N]
// [50256, +N)      dn[N]
// [100256, +E)     ae[E]
// [600256, +E)     perm[E]
// total ~4.4 MB

// K0: fold W_attn through W_shared; zero counters.
__global__ void k0_prep(const float* __restrict__ W_shared,
                        const float* __restrict__ W_attn,
                        float* __restrict__ uvecs,
                        int* __restrict__ counts,
                        int* __restrict__ cursor) {
    int t = threadIdx.x;
    if (t < 64) {
        float us = 0.f, ve = 0.f, ud = 0.f;
        for (int o = 0; o < 64; ++o) {
            float w = W_shared[o * 64 + t];
            us = fmaf(w, W_attn[o],        us);
            ve = fmaf(w, W_attn[64 + o],   ve);
            ud = fmaf(w, W_attn[128 + o],  ud);
        }
        uvecs[t] = us; uvecs[64 + t] = ve; uvecs[128 + t] = ud;
    } else if (t < 80) {
        counts[t - 64] = 0;
    } else if (t < 96) {
        cursor[t - 80] = 0;
    }
}

// K1: per-node score scalars + zero the output (replaces memset)
__global__ void k1_node(const float* __restrict__ h,
                        const float* __restrict__ uvecs,
                        float* __restrict__ sn, float* __restrict__ dn,
                        float4* __restrict__ out4) {
    int n = blockIdx.x * blockDim.x + threadIdx.x;
    if (n >= N_NODES) return;
    const float* hp = h + (size_t)n * DIM;
    float s = 0.f, d = 0.f;
#pragma unroll
    for (int i = 0; i < 64; i += 4) {
        float4 t = *(const float4*)(hp + i);
        s = fmaf(t.x, uvecs[i],     s); s = fmaf(t.y, uvecs[i + 1], s);
        s = fmaf(t.z, uvecs[i + 2], s); s = fmaf(t.w, uvecs[i + 3], s);
        d = fmaf(t.x, uvecs[128 + i],     d); d = fmaf(t.y, uvecs[128 + i + 1], d);
        d = fmaf(t.z, uvecs[128 + i + 2], d); d = fmaf(t.w, uvecs[128 + i + 3], d);
    }
    sn[n] = s; dn[n] = d;
    float4 z = make_float4(0.f, 0.f, 0.f, 0.f);
#pragma unroll
    for (int i = 0; i < 16; ++i) out4[(size_t)n * 16 + i] = z;
}

// K2: per-edge attention scalar ae[e] = sn[src]+dn[dst]+he[e]·v_e,
//     plus per-relation histogram. Wave-cooperative: 4 lanes per edge,
//     fully coalesced he reads (16 edges / wave / sweep).
__global__ void k2_ae(const float4* __restrict__ he4,
                      const int* __restrict__ src, const int* __restrict__ dst,
                      const int* __restrict__ rel,
                      const float* __restrict__ uvecs,
                      const float* __restrict__ sn, const float* __restrict__ dn,
                      float* __restrict__ ae, int* __restrict__ counts) {
    __shared__ int hist[NUM_RELS];
    int t = threadIdx.x;
    if (t < NUM_RELS) hist[t] = 0;
    __syncthreads();

    const int lane = t & 63;
    const int sub  = lane & 3;        // which quarter of the row
    const int eo   = lane >> 2;       // edge offset within the 16-edge group
    const int gw   = blockIdx.x * 4 + (t >> 6);       // global wave id
    const int nw   = gridDim.x * 4;

    // v_e quarter for this lane: uvecs[64 + sub*16 .. +16)
    float4 u0 = *(const float4*)(uvecs + 64 + sub * 16 + 0);
    float4 u1 = *(const float4*)(uvecs + 64 + sub * 16 + 4);
    float4 u2 = *(const float4*)(uvecs + 64 + sub * 16 + 8);
    float4 u3 = *(const float4*)(uvecs + 64 + sub * 16 + 12);

    for (int base = gw * 16; base < N_EDGES; base += nw * 16) {
        int e = base + eo;
        float p = 0.f;
        if (e < N_EDGES) {
            const float4* row = he4 + (size_t)e * 16 + sub * 4;
            float4 a = row[0], b = row[1], c = row[2], d = row[3];
            p = a.x*u0.x + a.y*u0.y + a.z*u0.z + a.w*u0.w
              + b.x*u1.x + b.y*u1.y + b.z*u1.z + b.w*u1.w
              + c.x*u2.x + c.y*u2.y + c.z*u2.z + c.w*u2.w
              + d.x*u3.x + d.y*u3.y + d.z*u3.z + d.w*u3.w;
        }
        p += __shfl_xor(p, 1, 64);
        p += __shfl_xor(p, 2, 64);
        if (sub == 0 && e < N_EDGES) {
            ae[e] = p + sn[src[e]] + dn[dst[e]];
            atomicAdd(&hist[rel[e]], 1);
        }
    }
    __syncthreads();
    if (t < NUM_RELS && hist[t]) atomicAdd(&counts[t], hist[t]);
}

// K3: exclusive scan of 16 counts
__global__ void k3_scan(const int* __restrict__ counts, int* __restrict__ offs) {
    int acc = 0;
    for (int r = 0; r < NUM_RELS; ++r) { offs[r] = acc; acc += counts[r]; }
    offs[NUM_RELS] = acc;
}

// K4: bucket edge ids by relation (1024-thread blocks -> few cursor atomics)
__global__ void k4_scatter(const int* __restrict__ rel,
                           const int* __restrict__ offs,
                           int* __restrict__ cursor,
                           int* __restrict__ perm) {
    __shared__ int hist[NUM_RELS];
    __shared__ int bbase[NUM_RELS];
    int t = threadIdx.x;
    if (t < NUM_RELS) hist[t] = 0;
    __syncthreads();
    int e = blockIdx.x * 1024 + t;
    int r = 0, lpos = 0;
    bool valid = (e < N_EDGES);
    if (valid) { r = rel[e]; lpos = atomicAdd(&hist[r], 1); }
    __syncthreads();
    if (t < NUM_RELS) bbase[t] = hist[t] ? atomicAdd(&cursor[t], hist[t]) : 0;
    __syncthreads();
    if (valid) perm[offs[r] + bbase[r] + lpos] = e;
}

// K5: main fused kernel. One wave = one relation; lane o holds W_rel[r][:,o]
// pinned in 64 VGPRs. 64-edge batches: coalesced record load, v_readlane
// broadcast, uniform (scalar) h-row loads, native fp32 atomics out.
__global__ __launch_bounds__(256, 4) void k5_main(
    const float* __restrict__ h,
    const int* __restrict__ src, const int* __restrict__ dst,
    const float* __restrict__ W_rel,
    const float* __restrict__ ae,
    const int* __restrict__ offs, const int* __restrict__ perm,
    float* __restrict__ out)
{
    const int lane = threadIdx.x & 63;
    const int wib  = __builtin_amdgcn_readfirstlane(threadIdx.x >> 6);
    const int r    = blockIdx.x & 15;
    const int g    = blockIdx.x >> 4;
    const int wr   = g * 4 + wib;                // wave index within relation
    const int WPR  = GPB * 4;                    // waves per relation

    // lane's column of W_rel[r]: w[i] = W_rel[r][i][lane] — pinned in VGPRs
    float w[64];
    const float* wb = W_rel + (size_t)r * (DIM * DIM) + lane;
#pragma unroll
    for (int i = 0; i < 64; ++i) w[i] = wb[i * 64];
#pragma unroll
    for (int i = 0; i < 64; ++i) asm volatile("" : "+v"(w[i]));   // force VGPR residency

    const int begin = offs[r];
    const int end   = offs[r + 1];

    for (int base = begin + wr * 64; base < end; base += WPR * 64) {
        // batch: lane l prefetches edge record base+l (coalesced + gathers)
        int e_l = 0, s_l = 0, d_l = 0; float a_l = 0.f;
        if (base + lane < end) {
            e_l = perm[base + lane];
            s_l = src[e_l];
            d_l = dst[e_l];
            a_l = ae[e_l];
        }
        const int kmax = min(64, end - base);
        for (int k = 0; k < kmax; ++k) {
            const int   si = __builtin_amdgcn_readlane(s_l, k);
            const int   di = __builtin_amdgcn_readlane(d_l, k);
            const float ak = __int_as_float(__builtin_amdgcn_readlane(__float_as_int(a_l), k));

            const float* hp = h + (size_t)si * DIM;   // wave-uniform -> s_load
            float a0 = 0.f, a1 = 0.f, a2 = 0.f, a3 = 0.f;
#pragma unroll
            for (int i = 0; i < 64; i += 4) {
                a0 = fmaf(hp[i],     w[i],     a0);
                a1 = fmaf(hp[i + 1], w[i + 1], a1);
                a2 = fmaf(hp[i + 2], w[i + 2], a2);
                a3 = fmaf(hp[i + 3], w[i + 3], a3);
            }
            const float dot = (a0 + a1) + (a2 + a3);
            unsafeAtomicAdd(out + (size_t)di * DIM + lane, ak * dot);
        }
    }
}

// K6: relu in place
__global__ void k6_relu(float4* __restrict__ out, int n4) {
    int i = blockIdx.x * blockDim.x + threadIdx.x;
    if (i < n4) {
        float4 v = out[i];
        v.x = fmaxf(v.x, 0.f); v.y = fmaxf(v.y, 0.f);
        v.z = fmaxf(v.z, 0.f); v.w = fmaxf(v.w, 0.f);
        out[i] = v;
    }
}

extern "C" void kernel_launch(void* const* d_in, const int* in_sizes, int n_in,
                              void* d_out, int out_size, void* d_ws, size_t ws_size,
                              hipStream_t stream) {
    const float* h        = (const float*)d_in[0];
    const float* he       = (const float*)d_in[1];
    const int*   src      = (const int*)d_in[2];
    const int*   dst      = (const int*)d_in[3];
    const int*   rel      = (const int*)d_in[4];
    const float* W_shared = (const float*)d_in[5];
    const float* W_attn   = (const float*)d_in[6];
    const float* W_rel    = (const float*)d_in[7];
    float*       out      = (float*)d_out;

    float* uvecs  = (float*)d_ws;
    int*   counts = (int*)d_ws + 192;
    int*   offs   = (int*)d_ws + 208;
    int*   cursor = (int*)d_ws + 228;
    float* sn     = (float*)d_ws + 256;
    float* dn     = (float*)d_ws + 50256;
    float* ae     = (float*)d_ws + 100256;
    int*   perm   = (int*)d_ws + 600256;

    k0_prep<<<1, 128, 0, stream>>>(W_shared, W_attn, uvecs, counts, cursor);
    k1_node<<<(N_NODES + 255) / 256, 256, 0, stream>>>(h, uvecs, sn, dn, (float4*)out);
    k2_ae<<<1024, 256, 0, stream>>>((const float4*)he, src, dst, rel, uvecs, sn, dn, ae, counts);
    k3_scan<<<1, 1, 0, stream>>>(counts, offs);
    k4_scatter<<<(N_EDGES + 1023) / 1024, 1024, 0, stream>>>(rel, offs, cursor, perm);
    k5_main<<<NUM_RELS * GPB, 256, 0, stream>>>(h, src, dst, W_rel, ae, offs, perm, out);
    int n4 = out_size / 4;
    k6_relu<<<(n4 + 255) / 256, 256, 0, stream>>>((float4*)out, n4);
}